// Round 1
// baseline (191.181 us; speedup 1.0000x reference)
//
#include <hip/hip_runtime.h>
#include <hip/hip_bf16.h>

// GCN SpMM: out[i,d] = sum_{e: rows[e]==i} vals[e] * embeds[cols[e], d]
// rows sorted ascending. E=1.6M, N=100k, D=64.

constexpr int D = 64;
constexpr int EDGES_PER_WAVE = 128;

__global__ __launch_bounds__(256) void zero_kernel(float* __restrict__ out, int n4) {
    // n4 = number of float4 elements
    int i = blockIdx.x * blockDim.x + threadIdx.x;
    int stride = gridDim.x * blockDim.x;
    float4 z = make_float4(0.f, 0.f, 0.f, 0.f);
    float4* o4 = (float4*)out;
    for (; i < n4; i += stride) o4[i] = z;
}

__global__ __launch_bounds__(256) void spmm_kernel(
    const int* __restrict__ rows,
    const int* __restrict__ cols,
    const float* __restrict__ vals,
    const float* __restrict__ embeds,
    float* __restrict__ out,
    int n_edges)
{
    const int lane = threadIdx.x & 63;
    const int wave_id = blockIdx.x * (blockDim.x >> 6) + (threadIdx.x >> 6);

    long e0 = (long)wave_id * EDGES_PER_WAVE;
    if (e0 >= n_edges) return;
    long e1 = e0 + EDGES_PER_WAVE;
    if (e1 > n_edges) e1 = n_edges;

    float acc = 0.f;
    int cur_row = -1;

    for (long base = e0; base < e1; base += 64) {
        long my_e = base + lane;
        int r = 0, c = 0;
        float v = 0.f;
        if (my_e < e1) {
            r = rows[my_e];
            c = cols[my_e];
            v = vals[my_e];
        }
        int cnt = (int)(e1 - base);
        if (cnt > 64) cnt = 64;
        for (int j = 0; j < cnt; ++j) {
            int   rj = __shfl(r, j);
            int   cj = __shfl(c, j);
            float vj = __shfl(v, j);
            if (rj != cur_row) {            // wave-uniform branch
                if (cur_row >= 0)
                    atomicAdd(&out[(long)cur_row * D + lane], acc);
                cur_row = rj;
                acc = 0.f;
            }
            acc += vj * embeds[(long)cj * D + lane];
        }
    }
    if (cur_row >= 0)
        atomicAdd(&out[(long)cur_row * D + lane], acc);
}

extern "C" void kernel_launch(void* const* d_in, const int* in_sizes, int n_in,
                              void* d_out, int out_size, void* d_ws, size_t ws_size,
                              hipStream_t stream) {
    const int*   rows   = (const int*)d_in[0];
    const int*   cols   = (const int*)d_in[1];
    const float* vals   = (const float*)d_in[2];
    const float* embeds = (const float*)d_in[3];
    float*       out    = (float*)d_out;

    const int n_edges = in_sizes[0];

    // 1) zero-init output (poisoned to 0xAA before every launch)
    int n4 = out_size / 4;                      // out_size = 6,400,000 -> divisible by 4
    int zb = (n4 + 255) / 256;
    if (zb > 1024) zb = 1024;
    zero_kernel<<<zb, 256, 0, stream>>>(out, n4);

    // 2) segmented SpMM
    int waves  = (n_edges + EDGES_PER_WAVE - 1) / EDGES_PER_WAVE;
    int blocks = (waves + 3) / 4;               // 4 waves per 256-thread block
    spmm_kernel<<<blocks, 256, 0, stream>>>(rows, cols, vals, embeds, out, n_edges);
}